// Round 6
// baseline (281.930 us; speedup 1.0000x reference)
//
#include <hip/hip_runtime.h>
#include <stdint.h>

#define B_   8
#define N_   8192
#define S_   2048
#define D1_  128
#define D2_  256
#define CIN_ 384
#define C1_  256
#define C2_  128
#define NSUB_ 4

typedef uint16_t u16;
typedef uint32_t u32;
typedef __attribute__((ext_vector_type(8))) short bf16x8;
typedef __attribute__((ext_vector_type(4))) float f32x4;

static __device__ __forceinline__ u16 f2bf(float f){
    union { float f; u32 u; } v; v.f = f;
    u32 r = v.u + 0x7FFF + ((v.u >> 16) & 1);
    return (u16)(r >> 16);
}
static __device__ __forceinline__ float bf2f(u16 h){
    union { u32 u; float f; } v; v.u = ((u32)h) << 16;
    return v.f;
}
static __device__ __forceinline__ uint4 pack8(const u16 h[8]){
    uint4 u;
    u.x = (u32)h[0] | ((u32)h[1] << 16);
    u.y = (u32)h[2] | ((u32)h[3] << 16);
    u.z = (u32)h[4] | ((u32)h[5] << 16);
    u.w = (u32)h[6] | ((u32)h[7] << 16);
    return u;
}
#define EXT8(dst, u) { dst[0]=bf2f((u16)(u).x); dst[1]=bf2f((u16)((u).x>>16)); \
                       dst[2]=bf2f((u16)(u).y); dst[3]=bf2f((u16)((u).y>>16)); \
                       dst[4]=bf2f((u16)(u).z); dst[5]=bf2f((u16)((u).z>>16)); \
                       dst[6]=bf2f((u16)(u).w); dst[7]=bf2f((u16)((u).w>>16)); }

// ---------------- prep: weights -> bf16 ----------------
__global__ void k_prep_w(const float* __restrict__ w1, const float* __restrict__ w2,
                         u16* __restrict__ w1bf, u16* __restrict__ w2bf){
    int i = blockIdx.x * 256 + threadIdx.x;
    if (i < C1_*CIN_) w1bf[i] = f2bf(w1[i]);
    if (i < C2_*C1_)  w2bf[i] = f2bf(w2[i]);
}

// ---------------- prep: points2 [b][d][s] -> p2t bf16 [b][s][d] ----------------
__global__ __launch_bounds__(256) void k_p2t(const float* __restrict__ p2, u16* __restrict__ p2t){
    __shared__ float t[32][33];
    int b = blockIdx.z, s0 = blockIdx.x * 32, d0 = blockIdx.y * 32;
    int tt = threadIdx.x;
    int r = tt >> 3, c4 = (tt & 7) * 4;
    const float* src = p2 + (((size_t)b*D2_ + d0 + r) * S_ + s0 + c4);
    float4 v = *(const float4*)src;
    t[r][c4+0]=v.x; t[r][c4+1]=v.y; t[r][c4+2]=v.z; t[r][c4+3]=v.w;
    __syncthreads();
    ushort4 o;
    o.x = f2bf(t[c4+0][r]); o.y = f2bf(t[c4+1][r]);
    o.z = f2bf(t[c4+2][r]); o.w = f2bf(t[c4+3][r]);
    u16* dst = p2t + (((size_t)b*S_ + s0 + r) * D2_ + d0 + c4);
    *(ushort4*)dst = o;
}

// ---------------- 3-NN search: 4 threads/query, 4 interleaved chains ----------------
// Selection arithmetic kept bit-identical to the passing version (round-3 lesson:
// any truncation of the distance compare flips 3rd/4th neighbors -> fails).
#define INS3G(dd, ss, D0,D1,D2,I0,I1,I2) do{ if ((dd) < D2){ if ((dd) < D1){ D2=D1; I2=I1; \
    if ((dd) < D0){ D1=D0; I1=I0; D0=(dd); I0=(ss); } else { D1=(dd); I1=(ss); } } \
    else { D2=(dd); I2=(ss); } } }while(0)

__global__ __launch_bounds__(256) void k_nn(const float* __restrict__ xyz1,
                                            const float* __restrict__ xyz2,
                                            int4* __restrict__ nn_idx4, float4* __restrict__ nn_w4){
    __shared__ float4 pt[S_];
    int b = blockIdx.y;
    int t = threadIdx.x;
    const float* xb = xyz2 + (size_t)b*3*S_;
    for (int i = t; i < S_; i += 256){
        float x = xb[i], y = xb[S_ + i], z = xb[2*S_ + i];
        pt[i] = make_float4(x, y, z, x*x + y*y + z*z);
    }
    __syncthreads();
    int nl = t >> 2, q = t & 3;              // 64 queries/block, 4 threads each
    int n = blockIdx.x * 64 + nl;
    const float* x1b = xyz1 + (size_t)b*3*N_;
    float px = x1b[n], py = x1b[N_ + n], pz = x1b[2*N_ + n];
    float n1 = px*px + py*py + pz*pz;
    float D0[4], D1[4], D2[4];
    int   I0[4], I1[4], I2[4];
    #pragma unroll
    for (int k = 0; k < 4; ++k){
        D0[k] = D1[k] = D2[k] = 3.4e38f;
        I0[k] = I1[k] = I2[k] = 0;
    }
    // quarter q scans s = q*512 + ((j + k + 2q) & 511): within any one instruction,
    // bank quad = 4(j+k) + 8q mod 32 is distinct across q -> conflict-free.
    const int sbase = q * 512, rot = q * 2;
    #pragma unroll 2
    for (int j = 0; j < 512; j += 4){
        #pragma unroll
        for (int k = 0; k < 4; ++k){
            int s = sbase + ((j + k + rot) & 511);
            float4 qa = pt[s];
            float dot = fmaf(px, qa.x, fmaf(py, qa.y, pz*qa.z));
            float dd  = fmaf(-2.f, dot, n1 + qa.w);
            INS3G(dd, s, D0[k],D1[k],D2[k], I0[k],I1[k],I2[k]);
        }
    }
    // merge chains 1..3 into chain 0
    #pragma unroll
    for (int k = 1; k < 4; ++k){
        INS3G(D0[k], I0[k], D0[0],D1[0],D2[0], I0[0],I1[0],I2[0]);
        INS3G(D1[k], I1[k], D0[0],D1[0],D2[0], I0[0],I1[0],I2[0]);
        INS3G(D2[k], I2[k], D0[0],D1[0],D2[0], I0[0],I1[0],I2[0]);
    }
    // merge across the 4 threads of this query
    #pragma unroll
    for (int m = 1; m <= 2; m <<= 1){
        float e0=__shfl_xor(D0[0],m), e1=__shfl_xor(D1[0],m), e2=__shfl_xor(D2[0],m);
        int   j0=__shfl_xor(I0[0],m), j1=__shfl_xor(I1[0],m), j2=__shfl_xor(I2[0],m);
        INS3G(e0, j0, D0[0],D1[0],D2[0], I0[0],I1[0],I2[0]);
        INS3G(e1, j1, D0[0],D1[0],D2[0], I0[0],I1[0],I2[0]);
        INS3G(e2, j2, D0[0],D1[0],D2[0], I0[0],I1[0],I2[0]);
    }
    if (q == 0){
        float r0 = 1.f/(D0[0]+1e-8f), r1 = 1.f/(D1[0]+1e-8f), r2 = 1.f/(D2[0]+1e-8f);
        float inv = 1.f/(r0+r1+r2);
        size_t base = (size_t)b*N_ + n;
        nn_idx4[base] = make_int4(I0[0], I1[0], I2[0], 0);
        nn_w4[base]   = make_float4(r0*inv, r1*inv, r2*inv, 0.f);
    }
}

// LDS swizzles: Xt row=768B, Zt row=512B
#define SWZ(nrow, kbyte)  ((((nrow)*768 + (kbyte))) ^ (((nrow)&7)<<4))
#define SWZ2(nrow, kbyte) ((((nrow)*512 + (kbyte))) ^ (((nrow)&7)<<4))

// ---------------- conv1: W-stationary, 8 waves, 256 points/block, 4 subtiles ----------------
// amdgpu_waves_per_eu(2,2): LDS (96KB) caps at 1 block/CU = 2 waves/EU anyway, so
// tell the compiler to use the full 256-VGPR budget instead of spilling at 128
// (round-5: VGPR_Count=128 vs ~220 demand -> scratch spills = 45K-cyc/subtile stall).
__global__ __launch_bounds__(512) __attribute__((amdgpu_waves_per_eu(2, 2)))
void k_conv1(const u16* __restrict__ w1bf,
    const float* __restrict__ points1, const u16* __restrict__ p2t,
    const int4* __restrict__ nn_idx4, const float4* __restrict__ nn_w4,
    u16* __restrict__ y1, float* __restrict__ part1){
    __shared__ char sm[96*1024];
    int t = threadIdx.x;
    int wave = t >> 6, lane = t & 63;
    // XCD swizzle: 256 blocks, vid=(x&7)*32+(x>>3) puts each batch's 32 blocks on
    // one XCD -> the 1MB/batch p2t gather slab stays L2-resident.
    int vid = (blockIdx.x & 7) * 32 + (blockIdx.x >> 3);
    int b = vid >> 5, n0g = (vid & 31) * 256;
    const int nlo = lane & 15, nhi = lane >> 4;

    // ---- W fragments persistent: wave owns out-ch [wave*32, wave*32+32)
    bf16x8 wfr[2][12];
    {
        const u16* wb = w1bf + ((size_t)(wave*32 + nlo))*CIN_ + nhi*8;
        #pragma unroll
        for (int mh = 0; mh < 2; ++mh)
            #pragma unroll
            for (int ks = 0; ks < 12; ++ks)
                wfr[mh][ks] = *(const bf16x8*)(wb + (size_t)mh*16*CIN_ + ks*32);
    }

    const int g8 = t & 15, pr = t >> 4;   // phase A roles: 8-ch group, row-pair
    const int rb = t >> 3, q8 = t & 7;    // phase B roles: row, 32-ch group

    float2 va2[8];
    uint4 uB[12];
    int4 nid; float4 nw;

    auto ISSUE_A = [&](int s){
        const float* pA = points1 + ((size_t)b*D1_ + g8*8)*N_ + n0g + s*64 + pr*2;
        #pragma unroll
        for (int j = 0; j < 8; ++j) va2[j] = *(const float2*)(pA + (size_t)j*N_);
        size_t nb = (size_t)b*N_ + n0g + s*64 + rb;
        nid = nn_idx4[nb]; nw = nn_w4[nb];
    };
    auto ISSUE_B = [&](){
        const u16* r0 = p2t + ((size_t)b*S_ + nid.x)*D2_ + q8*32;
        const u16* r1 = p2t + ((size_t)b*S_ + nid.y)*D2_ + q8*32;
        const u16* r2 = p2t + ((size_t)b*S_ + nid.z)*D2_ + q8*32;
        #pragma unroll
        for (int c = 0; c < 4; ++c){
            uB[c]   = *(const uint4*)(r0 + c*8);
            uB[4+c] = *(const uint4*)(r1 + c*8);
            uB[8+c] = *(const uint4*)(r2 + c*8);
        }
    };
    auto COMBINE = [&](char* X){
        #pragma unroll
        for (int e = 0; e < 2; ++e){
            u16 h[8];
            #pragma unroll
            for (int j = 0; j < 8; ++j) h[j] = f2bf(e ? va2[j].y : va2[j].x);
            *(uint4*)(X + SWZ(pr*2+e, g8*16)) = pack8(h);
        }
        #pragma unroll
        for (int c = 0; c < 4; ++c){
            float f0[8], f1[8], f2v[8];
            EXT8(f0, uB[c]); EXT8(f1, uB[4+c]); EXT8(f2v, uB[8+c]);
            u16 h[8];
            #pragma unroll
            for (int e = 0; e < 8; ++e)
                h[e] = f2bf(fmaf(nw.x, f0[e], fmaf(nw.y, f1[e], nw.z*f2v[e])));
            *(uint4*)(X + SWZ(rb, (128 + q8*32 + c*8)*2)) = pack8(h);
        }
    };

    char* Xc = sm;
    char* Xn = sm + 48*1024;

    ISSUE_A(0);
    ISSUE_B();
    COMBINE(Xc);
    __syncthreads();

    float s1a[2][4] = {{0,0,0,0},{0,0,0,0}}, s2a[2][4] = {{0,0,0,0},{0,0,0,0}};
    const int kgB = nhi*16;

    #pragma unroll 1
    for (int s = 0; s < NSUB_; ++s){
        if (s+1 < NSUB_) ISSUE_A(s+1);
        #pragma unroll
        for (int rowg = 0; rowg < 4; ++rowg){
            int nrow = rowg*16 + nlo;
            f32x4 acc0 = {0.f,0.f,0.f,0.f}, acc1 = {0.f,0.f,0.f,0.f};
            #pragma unroll
            for (int hf = 0; hf < 2; ++hf){
                bf16x8 xf[6];
                #pragma unroll
                for (int k6 = 0; k6 < 6; ++k6)
                    xf[k6] = *(const bf16x8*)(Xc + SWZ(nrow, (hf*6+k6)*64 + kgB));
                #pragma unroll
                for (int k6 = 0; k6 < 6; ++k6){
                    acc0 = __builtin_amdgcn_mfma_f32_16x16x32_bf16(wfr[0][hf*6+k6], xf[k6], acc0, 0,0,0);
                    acc1 = __builtin_amdgcn_mfma_f32_16x16x32_bf16(wfr[1][hf*6+k6], xf[k6], acc1, 0,0,0);
                }
            }
            if (s+1 < NSUB_ && rowg == 1) ISSUE_B();
            int n = n0g + s*64 + nrow;
            u16 h0[4], h1[4];
            #pragma unroll
            for (int r = 0; r < 4; ++r){
                h0[r] = f2bf(acc0[r]); h1[r] = f2bf(acc1[r]);
                s1a[0][r] += acc0[r]; s2a[0][r] += acc0[r]*acc0[r];
                s1a[1][r] += acc1[r]; s2a[1][r] += acc1[r]*acc1[r];
            }
            u16* yp = y1 + ((size_t)b*N_ + n)*C1_ + wave*32 + nhi*4;
            uint2 p0, p1;
            p0.x = (u32)h0[0] | ((u32)h0[1]<<16); p0.y = (u32)h0[2] | ((u32)h0[3]<<16);
            p1.x = (u32)h1[0] | ((u32)h1[1]<<16); p1.y = (u32)h1[2] | ((u32)h1[3]<<16);
            *(uint2*)yp = p0;
            *(uint2*)(yp + 16) = p1;
        }
        if (s+1 < NSUB_) COMBINE(Xn);
        __syncthreads();
        char* tmp = Xc; Xc = Xn; Xn = tmp;
    }

    // ---- BN1 partials: reduce over the 16-lane (n) group
    int blk = vid;
    #pragma unroll
    for (int mh = 0; mh < 2; ++mh)
        #pragma unroll
        for (int r = 0; r < 4; ++r){
            float a = s1a[mh][r], qv = s2a[mh][r];
            #pragma unroll
            for (int m = 1; m <= 8; m <<= 1){ a += __shfl_xor(a, m); qv += __shfl_xor(qv, m); }
            if (nlo == 0){
                int ch = wave*32 + mh*16 + nhi*4 + r;
                part1[(size_t)blk*C1_ + ch] = a;
                part1[(size_t)256*C1_ + (size_t)blk*C1_ + ch] = qv;
            }
        }
}

// ---------------- conv2: W-stationary, z = relu(bn1(y1)) on the fly ----------------
__global__ __launch_bounds__(512, 4) void k_conv2(const u16* __restrict__ w2bf,
    const u16* __restrict__ y1, const float* __restrict__ a1c1,
    u16* __restrict__ z2bf, float* __restrict__ part2){
    __shared__ char sm[64*1024];
    int t = threadIdx.x;
    int wave = t >> 6, lane = t & 63;
    int b = blockIdx.y, n0g = blockIdx.x * 256;
    const int nlo = lane & 15, nhi = lane >> 4;

    bf16x8 wfr[8];
    {
        const u16* wb = w2bf + ((size_t)(wave*16 + nlo))*C1_ + nhi*8;
        #pragma unroll
        for (int ks = 0; ks < 8; ++ks) wfr[ks] = *(const bf16x8*)(wb + ks*32);
    }

    const int r2 = t >> 4, q16 = t & 15;   // build roles: row-pair, 16-ch group
    float la8[16], lc8[16];
    {
        const float* ap = a1c1 + q16*16;
        #pragma unroll
        for (int c = 0; c < 4; ++c){
            *(float4*)(la8 + c*4) = *(const float4*)(ap + c*4);
            *(float4*)(lc8 + c*4) = *(const float4*)(ap + 256 + c*4);
        }
    }

    uint4 uy[4];
    auto ISSUE_Y = [&](int s){
        const u16* yp = y1 + ((size_t)b*N_ + n0g + s*64 + r2*2)*C1_ + q16*16;
        #pragma unroll
        for (int e = 0; e < 2; ++e)
            #pragma unroll
            for (int c = 0; c < 2; ++c)
                uy[e*2+c] = *(const uint4*)(yp + (size_t)e*C1_ + c*8);
    };
    auto COMBINE = [&](char* Z){
        #pragma unroll
        for (int e = 0; e < 2; ++e)
            #pragma unroll
            for (int c = 0; c < 2; ++c){
                float f[8]; EXT8(f, uy[e*2+c]);
                u16 h[8];
                #pragma unroll
                for (int k = 0; k < 8; ++k){
                    float z = fmaf(la8[c*8+k], f[k], lc8[c*8+k]);
                    h[k] = f2bf(z > 0.f ? z : 0.f);
                }
                *(uint4*)(Z + SWZ2(r2*2+e, q16*32 + c*16)) = pack8(h);
            }
    };

    char* Zc = sm;
    char* Zn = sm + 32*1024;

    ISSUE_Y(0);
    COMBINE(Zc);
    __syncthreads();

    float s1a[4] = {0,0,0,0}, s2a[4] = {0,0,0,0};
    const int kgB = nhi*16;

    #pragma unroll 1
    for (int s = 0; s < NSUB_; ++s){
        if (s+1 < NSUB_) ISSUE_Y(s+1);
        #pragma unroll
        for (int rowg = 0; rowg < 4; ++rowg){
            int nrow = rowg*16 + nlo;
            f32x4 acc = {0.f,0.f,0.f,0.f};
            #pragma unroll
            for (int hf = 0; hf < 2; ++hf){
                bf16x8 xf[4];
                #pragma unroll
                for (int k4 = 0; k4 < 4; ++k4)
                    xf[k4] = *(const bf16x8*)(Zc + SWZ2(nrow, (hf*4+k4)*64 + kgB));
                #pragma unroll
                for (int k4 = 0; k4 < 4; ++k4)
                    acc = __builtin_amdgcn_mfma_f32_16x16x32_bf16(wfr[hf*4+k4], xf[k4], acc, 0,0,0);
            }
            int n = n0g + s*64 + nrow;
            u16 h[4];
            #pragma unroll
            for (int r = 0; r < 4; ++r){
                h[r] = f2bf(acc[r]);
                s1a[r] += acc[r]; s2a[r] += acc[r]*acc[r];
            }
            uint2 p;
            p.x = (u32)h[0] | ((u32)h[1]<<16); p.y = (u32)h[2] | ((u32)h[3]<<16);
            *(uint2*)(z2bf + ((size_t)b*N_ + n)*C2_ + wave*16 + nhi*4) = p;
        }
        if (s+1 < NSUB_) COMBINE(Zn);
        __syncthreads();
        char* tmp = Zc; Zc = Zn; Zn = tmp;
    }

    int blk = blockIdx.y * gridDim.x + blockIdx.x;
    #pragma unroll
    for (int r = 0; r < 4; ++r){
        float a = s1a[r], qv = s2a[r];
        #pragma unroll
        for (int m = 1; m <= 8; m <<= 1){ a += __shfl_xor(a, m); qv += __shfl_xor(qv, m); }
        if (nlo == 0){
            int ch = wave*16 + nhi*4 + r;
            part2[(size_t)blk*C2_ + ch] = a;
            part2[(size_t)256*C2_ + (size_t)blk*C2_ + ch] = qv;
        }
    }
}

// ---------------- finalize BN stats ----------------
__global__ void k_finalize(const float* __restrict__ part, int C, int NB, float count,
                           const float* __restrict__ gamma, const float* __restrict__ beta,
                           float* __restrict__ ac){
    int o = blockIdx.x, t = threadIdx.x;
    float s1 = 0.f, s2 = 0.f;
    for (int i = t; i < NB; i += 256){
        s1 += part[(size_t)i*C + o];
        s2 += part[(size_t)NB*C + (size_t)i*C + o];
    }
    #pragma unroll
    for (int m = 1; m < 64; m <<= 1){ s1 += __shfl_xor(s1, m); s2 += __shfl_xor(s2, m); }
    __shared__ float ls[8];
    int wave = t >> 6, lane = t & 63;
    if (lane == 0){ ls[wave] = s1; ls[4+wave] = s2; }
    __syncthreads();
    if (t == 0){
        s1 = ls[0]+ls[1]+ls[2]+ls[3];
        s2 = ls[4]+ls[5]+ls[6]+ls[7];
        float mean = s1 / count;
        float var  = s2 / count - mean*mean;
        float inv  = rsqrtf(var + 1e-5f);
        float a = gamma[o] * inv;
        ac[o] = a;
        ac[C + o] = beta[o] - mean*a;
    }
}

// ---------------- apply BN2+ReLU with transpose: z2bf [b][n][ch] -> out [b][ch][n] f32 ----------------
__global__ __launch_bounds__(256) void k_apply(const u16* __restrict__ z2bf,
                                               const float* __restrict__ a2c2,
                                               float* __restrict__ out){
    __shared__ float T[128][65];
    __shared__ float la[C2_], lc[C2_];
    int b = blockIdx.y, n0 = blockIdx.x * 64;
    int t = threadIdx.x;
    if (t < C2_){ la[t] = a2c2[t]; lc[t] = a2c2[C2_ + t]; }
    __syncthreads();
    int ck = t & 15, ng = t >> 4;
    #pragma unroll
    for (int g = 0; g < 4; ++g){
        int n = g*16 + ng;
        uint4 v = *(const uint4*)(z2bf + ((size_t)b*N_ + n0 + n)*C2_ + ck*8);
        float f[8]; EXT8(f, v);
        #pragma unroll
        for (int e = 0; e < 8; ++e){
            int ch = ck*8 + e;
            T[ch][n] = fmaxf(fmaf(la[ch], f[e], lc[ch]), 0.f);
        }
    }
    __syncthreads();
    #pragma unroll
    for (int g = 0; g < 8; ++g){
        int id = g*256 + t;
        int ch = id >> 4, f4 = id & 15;
        float4 o;
        o.x = T[ch][f4*4+0]; o.y = T[ch][f4*4+1];
        o.z = T[ch][f4*4+2]; o.w = T[ch][f4*4+3];
        *(float4*)(out + ((size_t)b*C2_ + ch)*N_ + n0 + f4*4) = o;
    }
}

extern "C" void kernel_launch(void* const* d_in, const int* in_sizes, int n_in,
                              void* d_out, int out_size, void* d_ws, size_t ws_size,
                              hipStream_t stream){
    const float* xyz1    = (const float*)d_in[0];
    const float* xyz2    = (const float*)d_in[1];
    const float* points1 = (const float*)d_in[2];
    const float* points2 = (const float*)d_in[3];
    const float* w1      = (const float*)d_in[4];
    const float* gamma1  = (const float*)d_in[6];
    const float* beta1   = (const float*)d_in[7];
    const float* w2      = (const float*)d_in[8];
    const float* gamma2  = (const float*)d_in[10];
    const float* beta2   = (const float*)d_in[11];
    float* outp = (float*)d_out;

    char* ws = (char*)d_ws;
    size_t off = 0;
    auto take = [&](size_t sz) -> void* {
        void* p = ws + off;
        off = (off + sz + 255) & ~(size_t)255;
        return p;
    };
    int4*   nn_idx4 = (int4*)  take((size_t)B_*N_*16);
    float4* nn_w4   = (float4*)take((size_t)B_*N_*16);
    u16*    w1bf    = (u16*)   take((size_t)C1_*CIN_*2);
    u16*    w2bf    = (u16*)   take((size_t)C2_*C1_*2);
    u16*    p2t     = (u16*)   take((size_t)B_*S_*D2_*2);
    u16*    y1      = (u16*)   take((size_t)B_*N_*C1_*2);
    u16*    z2bf    = (u16*)   take((size_t)B_*N_*C2_*2);
    float*  part1   = (float*) take((size_t)2*256*C1_*4);
    float*  part2   = (float*) take((size_t)2*256*C2_*4);
    float*  a1c1    = (float*) take((size_t)2*C1_*4);
    float*  a2c2    = (float*) take((size_t)2*C2_*4);

    hipLaunchKernelGGL(k_prep_w, dim3(384), dim3(256), 0, stream, w1, w2, w1bf, w2bf);
    hipLaunchKernelGGL(k_p2t, dim3(S_/32, D2_/32, B_), dim3(256), 0, stream, points2, p2t);
    hipLaunchKernelGGL(k_nn, dim3(N_/64, B_), dim3(256), 0, stream, xyz1, xyz2, nn_idx4, nn_w4);
    hipLaunchKernelGGL(k_conv1, dim3(256), dim3(512), 0, stream,
                       w1bf, points1, p2t, nn_idx4, nn_w4, y1, part1);
    hipLaunchKernelGGL(k_finalize, dim3(C1_), dim3(256), 0, stream,
                       part1, C1_, 256, (float)(B_*N_), gamma1, beta1, a1c1);
    hipLaunchKernelGGL(k_conv2, dim3(N_/256, B_), dim3(512), 0, stream,
                       w2bf, y1, a1c1, z2bf, part2);
    hipLaunchKernelGGL(k_finalize, dim3(C2_), dim3(256), 0, stream,
                       part2, C2_, 256, (float)(B_*N_), gamma2, beta2, a2c2);
    hipLaunchKernelGGL(k_apply, dim3(N_/64, B_), dim3(256), 0, stream, z2bf, a2c2, outp);
    (void)in_sizes; (void)n_in; (void)out_size; (void)ws_size; (void)d_in;
}

// Round 7
// 212.575 us; speedup vs baseline: 1.3263x; 1.3263x over previous
//
#include <hip/hip_runtime.h>
#include <stdint.h>

#define B_   8
#define N_   8192
#define S_   2048
#define D1_  128
#define D2_  256
#define CIN_ 384
#define C1_  256
#define C2_  128
#define NSUB_ 4

typedef uint16_t u16;
typedef uint32_t u32;
typedef __attribute__((ext_vector_type(8))) short bf16x8;
typedef __attribute__((ext_vector_type(4))) float f32x4;

static __device__ __forceinline__ u16 f2bf(float f){
    union { float f; u32 u; } v; v.f = f;
    u32 r = v.u + 0x7FFF + ((v.u >> 16) & 1);
    return (u16)(r >> 16);
}
static __device__ __forceinline__ float bf2f(u16 h){
    union { u32 u; float f; } v; v.u = ((u32)h) << 16;
    return v.f;
}
static __device__ __forceinline__ uint4 pack8(const u16 h[8]){
    uint4 u;
    u.x = (u32)h[0] | ((u32)h[1] << 16);
    u.y = (u32)h[2] | ((u32)h[3] << 16);
    u.z = (u32)h[4] | ((u32)h[5] << 16);
    u.w = (u32)h[6] | ((u32)h[7] << 16);
    return u;
}
#define EXT8(dst, u) { dst[0]=bf2f((u16)(u).x); dst[1]=bf2f((u16)((u).x>>16)); \
                       dst[2]=bf2f((u16)(u).y); dst[3]=bf2f((u16)((u).y>>16)); \
                       dst[4]=bf2f((u16)(u).z); dst[5]=bf2f((u16)((u).z>>16)); \
                       dst[6]=bf2f((u16)(u).w); dst[7]=bf2f((u16)((u).w>>16)); }

static __device__ __forceinline__ float med3f(float a, float b, float c){
    float d;
    asm("v_med3_f32 %0, %1, %2, %3" : "=v"(d) : "v"(a), "v"(b), "v"(c));
    return d;
}

// ---------------- prep: weights -> bf16 ----------------
__global__ void k_prep_w(const float* __restrict__ w1, const float* __restrict__ w2,
                         u16* __restrict__ w1bf, u16* __restrict__ w2bf){
    int i = blockIdx.x * 256 + threadIdx.x;
    if (i < C1_*CIN_) w1bf[i] = f2bf(w1[i]);
    if (i < C2_*C1_)  w2bf[i] = f2bf(w2[i]);
}

// ---------------- prep: points2 [b][d][s] -> p2t bf16 [b][s][d] ----------------
__global__ __launch_bounds__(256) void k_p2t(const float* __restrict__ p2, u16* __restrict__ p2t){
    __shared__ float t[32][33];
    int b = blockIdx.z, s0 = blockIdx.x * 32, d0 = blockIdx.y * 32;
    int tt = threadIdx.x;
    int r = tt >> 3, c4 = (tt & 7) * 4;
    const float* src = p2 + (((size_t)b*D2_ + d0 + r) * S_ + s0 + c4);
    float4 v = *(const float4*)src;
    t[r][c4+0]=v.x; t[r][c4+1]=v.y; t[r][c4+2]=v.z; t[r][c4+3]=v.w;
    __syncthreads();
    ushort4 o;
    o.x = f2bf(t[c4+0][r]); o.y = f2bf(t[c4+1][r]);
    o.z = f2bf(t[c4+2][r]); o.w = f2bf(t[c4+3][r]);
    u16* dst = p2t + (((size_t)b*S_ + s0 + r) * D2_ + d0 + c4);
    *(ushort4*)dst = o;
}

// ---------------- 3-NN search: score-max formulation, med3 sorted-insert ----------------
// Rank by score = dot(p,q) - 0.5*|q|^2 (monotone in -dist for fixed query; 0.5*
// scaling is exponent-exact). All compares exact f32 (round-3 lesson). Padded LDS
// [4][513] float4: quarter bases differ by 8208B -> bank quads disjoint across the
// 4 threads of a query, broadcast within; linear scan => immediate-offset ds_reads.
// Max-insert: with M0>=M1>=M2, M1'=med3(M0,M1,sc), M2'=med3(M1,M2,sc), M0'=max.
#define INSMAX(sc, s) do{ \
    bool c2 = (sc) > M2, c1 = (sc) > M1, c0 = (sc) > M0; \
    int I2n = c2 ? (c1 ? I1 : (s)) : I2; \
    int I1n = c1 ? (c0 ? I0 : (s)) : I1; \
    int I0n = c0 ? (s) : I0; \
    float M2n = med3f(M1, M2, (sc)); \
    float M1n = med3f(M0, M1, (sc)); \
    M0 = fmaxf(M0, (sc)); \
    M1 = M1n; M2 = M2n; I0 = I0n; I1 = I1n; I2 = I2n; \
}while(0)
#define INSMAXB(sc, s) do{ \
    bool c2 = (sc) > N2, c1 = (sc) > N1, c0 = (sc) > N0; \
    int J2n = c2 ? (c1 ? J1 : (s)) : J2; \
    int J1n = c1 ? (c0 ? J0 : (s)) : J1; \
    int J0n = c0 ? (s) : J0; \
    float N2n = med3f(N1, N2, (sc)); \
    float N1n = med3f(N0, N1, (sc)); \
    N0 = fmaxf(N0, (sc)); \
    N1 = N1n; N2 = N2n; J0 = J0n; J1 = J1n; J2 = J2n; \
}while(0)

__global__ __launch_bounds__(256) void k_nn(const float* __restrict__ xyz1,
                                            const float* __restrict__ xyz2,
                                            int4* __restrict__ nn_idx4, float4* __restrict__ nn_w4){
    __shared__ float4 pt[4*513];             // quarter q at pt + q*513 (16B pad between)
    int b = blockIdx.y;
    int t = threadIdx.x;
    const float* xb = xyz2 + (size_t)b*3*S_;
    for (int i = t; i < S_; i += 256){
        float x = xb[i], y = xb[S_ + i], z = xb[2*S_ + i];
        float hw = 0.5f*(x*x + y*y + z*z);
        pt[(i >> 9)*513 + (i & 511)] = make_float4(x, y, z, hw);
    }
    __syncthreads();
    int nl = t >> 2, q = t & 3;              // 64 queries/block, 4 threads each
    int n = blockIdx.x * 64 + nl;
    const float* x1b = xyz1 + (size_t)b*3*N_;
    float px = x1b[n], py = x1b[N_ + n], pz = x1b[2*N_ + n];
    float n1 = px*px + py*py + pz*pz;
    // two interleaved chains (even/odd j) for dep-chain ILP
    float M0 = -3.4e38f, M1 = -3.4e38f, M2 = -3.4e38f;
    float N0 = -3.4e38f, N1 = -3.4e38f, N2 = -3.4e38f;
    int I0 = 0, I1 = 0, I2 = 0, J0 = 0, J1 = 0, J2 = 0;
    const float4* ptq = pt + q*513;
    #pragma unroll 4
    for (int j = 0; j < 512; j += 2){
        float4 qa = ptq[j];
        float4 qb = ptq[j+1];
        float sa = fmaf(px, qa.x, fmaf(py, qa.y, fmaf(pz, qa.z, -qa.w)));
        float sb = fmaf(px, qb.x, fmaf(py, qb.y, fmaf(pz, qb.z, -qb.w)));
        INSMAX(sa, j);
        INSMAXB(sb, j+1);
    }
    // merge chain B into A (ascending index order preserved: A even, B odd)
    INSMAX(N0, J0); INSMAX(N1, J1); INSMAX(N2, J2);
    // local j -> global s
    int sQ = q * 512;
    I0 += sQ; I1 += sQ; I2 += sQ;
    // merge across the 4 threads of this query; strict > keeps lower-q (lower
    // index) on exact score ties, matching stable top_k
    #pragma unroll
    for (int m = 1; m <= 2; m <<= 1){
        float e0=__shfl_xor(M0,m), e1=__shfl_xor(M1,m), e2=__shfl_xor(M2,m);
        int   j0=__shfl_xor(I0,m), j1=__shfl_xor(I1,m), j2=__shfl_xor(I2,m);
        INSMAX(e0, j0); INSMAX(e1, j1); INSMAX(e2, j2);
    }
    if (q == 0){
        float d0 = fmaf(-2.f, M0, n1);
        float d1 = fmaf(-2.f, M1, n1);
        float d2 = fmaf(-2.f, M2, n1);
        float r0 = 1.f/(d0+1e-8f), r1 = 1.f/(d1+1e-8f), r2 = 1.f/(d2+1e-8f);
        float inv = 1.f/(r0+r1+r2);
        size_t base = (size_t)b*N_ + n;
        nn_idx4[base] = make_int4(I0, I1, I2, 0);
        nn_w4[base]   = make_float4(r0*inv, r1*inv, r2*inv, 0.f);
    }
}

// LDS swizzles: Xt row=768B, Zt row=512B
#define SWZ(nrow, kbyte)  ((((nrow)*768 + (kbyte))) ^ (((nrow)&7)<<4))
#define SWZ2(nrow, kbyte) ((((nrow)*512 + (kbyte))) ^ (((nrow)&7)<<4))

// ---------------- conv1: W-stationary, 8 waves, 256 points/block, 4 subtiles ----------------
// amdgpu_waves_per_eu(2,2): LDS (96KB) caps at 1 block/CU = 2 waves/EU anyway, so
// tell the compiler to use the full 256-VGPR budget instead of spilling at 128
// (round-5: VGPR_Count=128 vs ~220 demand -> scratch spills = 45K-cyc/subtile stall).
__global__ __launch_bounds__(512) __attribute__((amdgpu_waves_per_eu(2, 2)))
void k_conv1(const u16* __restrict__ w1bf,
    const float* __restrict__ points1, const u16* __restrict__ p2t,
    const int4* __restrict__ nn_idx4, const float4* __restrict__ nn_w4,
    u16* __restrict__ y1, float* __restrict__ part1){
    __shared__ char sm[96*1024];
    int t = threadIdx.x;
    int wave = t >> 6, lane = t & 63;
    // XCD swizzle: 256 blocks, vid=(x&7)*32+(x>>3) puts each batch's 32 blocks on
    // one XCD -> the 1MB/batch p2t gather slab stays L2-resident.
    int vid = (blockIdx.x & 7) * 32 + (blockIdx.x >> 3);
    int b = vid >> 5, n0g = (vid & 31) * 256;
    const int nlo = lane & 15, nhi = lane >> 4;

    // ---- W fragments persistent: wave owns out-ch [wave*32, wave*32+32)
    bf16x8 wfr[2][12];
    {
        const u16* wb = w1bf + ((size_t)(wave*32 + nlo))*CIN_ + nhi*8;
        #pragma unroll
        for (int mh = 0; mh < 2; ++mh)
            #pragma unroll
            for (int ks = 0; ks < 12; ++ks)
                wfr[mh][ks] = *(const bf16x8*)(wb + (size_t)mh*16*CIN_ + ks*32);
    }

    const int g8 = t & 15, pr = t >> 4;   // phase A roles: 8-ch group, row-pair
    const int rb = t >> 3, q8 = t & 7;    // phase B roles: row, 32-ch group

    float2 va2[8];
    uint4 uB[12];
    int4 nid; float4 nw;

    auto ISSUE_A = [&](int s){
        const float* pA = points1 + ((size_t)b*D1_ + g8*8)*N_ + n0g + s*64 + pr*2;
        #pragma unroll
        for (int j = 0; j < 8; ++j) va2[j] = *(const float2*)(pA + (size_t)j*N_);
        size_t nb = (size_t)b*N_ + n0g + s*64 + rb;
        nid = nn_idx4[nb]; nw = nn_w4[nb];
    };
    auto ISSUE_B = [&](){
        const u16* r0 = p2t + ((size_t)b*S_ + nid.x)*D2_ + q8*32;
        const u16* r1 = p2t + ((size_t)b*S_ + nid.y)*D2_ + q8*32;
        const u16* r2 = p2t + ((size_t)b*S_ + nid.z)*D2_ + q8*32;
        #pragma unroll
        for (int c = 0; c < 4; ++c){
            uB[c]   = *(const uint4*)(r0 + c*8);
            uB[4+c] = *(const uint4*)(r1 + c*8);
            uB[8+c] = *(const uint4*)(r2 + c*8);
        }
    };
    auto COMBINE = [&](char* X){
        #pragma unroll
        for (int e = 0; e < 2; ++e){
            u16 h[8];
            #pragma unroll
            for (int j = 0; j < 8; ++j) h[j] = f2bf(e ? va2[j].y : va2[j].x);
            *(uint4*)(X + SWZ(pr*2+e, g8*16)) = pack8(h);
        }
        #pragma unroll
        for (int c = 0; c < 4; ++c){
            float f0[8], f1[8], f2v[8];
            EXT8(f0, uB[c]); EXT8(f1, uB[4+c]); EXT8(f2v, uB[8+c]);
            u16 h[8];
            #pragma unroll
            for (int e = 0; e < 8; ++e)
                h[e] = f2bf(fmaf(nw.x, f0[e], fmaf(nw.y, f1[e], nw.z*f2v[e])));
            *(uint4*)(X + SWZ(rb, (128 + q8*32 + c*8)*2)) = pack8(h);
        }
    };

    char* Xc = sm;
    char* Xn = sm + 48*1024;

    ISSUE_A(0);
    ISSUE_B();
    COMBINE(Xc);
    __syncthreads();

    float s1a[2][4] = {{0,0,0,0},{0,0,0,0}}, s2a[2][4] = {{0,0,0,0},{0,0,0,0}};
    const int kgB = nhi*16;

    #pragma unroll 1
    for (int s = 0; s < NSUB_; ++s){
        if (s+1 < NSUB_) ISSUE_A(s+1);
        #pragma unroll
        for (int rowg = 0; rowg < 4; ++rowg){
            int nrow = rowg*16 + nlo;
            f32x4 acc0 = {0.f,0.f,0.f,0.f}, acc1 = {0.f,0.f,0.f,0.f};
            #pragma unroll
            for (int hf = 0; hf < 2; ++hf){
                bf16x8 xf[6];
                #pragma unroll
                for (int k6 = 0; k6 < 6; ++k6)
                    xf[k6] = *(const bf16x8*)(Xc + SWZ(nrow, (hf*6+k6)*64 + kgB));
                #pragma unroll
                for (int k6 = 0; k6 < 6; ++k6){
                    acc0 = __builtin_amdgcn_mfma_f32_16x16x32_bf16(wfr[0][hf*6+k6], xf[k6], acc0, 0,0,0);
                    acc1 = __builtin_amdgcn_mfma_f32_16x16x32_bf16(wfr[1][hf*6+k6], xf[k6], acc1, 0,0,0);
                }
            }
            if (s+1 < NSUB_ && rowg == 1) ISSUE_B();
            int n = n0g + s*64 + nrow;
            u16 h0[4], h1[4];
            #pragma unroll
            for (int r = 0; r < 4; ++r){
                h0[r] = f2bf(acc0[r]); h1[r] = f2bf(acc1[r]);
                s1a[0][r] += acc0[r]; s2a[0][r] += acc0[r]*acc0[r];
                s1a[1][r] += acc1[r]; s2a[1][r] += acc1[r]*acc1[r];
            }
            u16* yp = y1 + ((size_t)b*N_ + n)*C1_ + wave*32 + nhi*4;
            uint2 p0, p1;
            p0.x = (u32)h0[0] | ((u32)h0[1]<<16); p0.y = (u32)h0[2] | ((u32)h0[3]<<16);
            p1.x = (u32)h1[0] | ((u32)h1[1]<<16); p1.y = (u32)h1[2] | ((u32)h1[3]<<16);
            *(uint2*)yp = p0;
            *(uint2*)(yp + 16) = p1;
        }
        if (s+1 < NSUB_) COMBINE(Xn);
        __syncthreads();
        char* tmp = Xc; Xc = Xn; Xn = tmp;
    }

    // ---- BN1 partials: reduce over the 16-lane (n) group
    int blk = vid;
    #pragma unroll
    for (int mh = 0; mh < 2; ++mh)
        #pragma unroll
        for (int r = 0; r < 4; ++r){
            float a = s1a[mh][r], qv = s2a[mh][r];
            #pragma unroll
            for (int m = 1; m <= 8; m <<= 1){ a += __shfl_xor(a, m); qv += __shfl_xor(qv, m); }
            if (nlo == 0){
                int ch = wave*32 + mh*16 + nhi*4 + r;
                part1[(size_t)blk*C1_ + ch] = a;
                part1[(size_t)256*C1_ + (size_t)blk*C1_ + ch] = qv;
            }
        }
}

// ---------------- conv2: W-stationary, z = relu(bn1(y1)) on the fly ----------------
__global__ __launch_bounds__(512, 4) void k_conv2(const u16* __restrict__ w2bf,
    const u16* __restrict__ y1, const float* __restrict__ a1c1,
    u16* __restrict__ z2bf, float* __restrict__ part2){
    __shared__ char sm[64*1024];
    int t = threadIdx.x;
    int wave = t >> 6, lane = t & 63;
    int b = blockIdx.y, n0g = blockIdx.x * 256;
    const int nlo = lane & 15, nhi = lane >> 4;

    bf16x8 wfr[8];
    {
        const u16* wb = w2bf + ((size_t)(wave*16 + nlo))*C1_ + nhi*8;
        #pragma unroll
        for (int ks = 0; ks < 8; ++ks) wfr[ks] = *(const bf16x8*)(wb + ks*32);
    }

    const int r2 = t >> 4, q16 = t & 15;   // build roles: row-pair, 16-ch group
    float la8[16], lc8[16];
    {
        const float* ap = a1c1 + q16*16;
        #pragma unroll
        for (int c = 0; c < 4; ++c){
            *(float4*)(la8 + c*4) = *(const float4*)(ap + c*4);
            *(float4*)(lc8 + c*4) = *(const float4*)(ap + 256 + c*4);
        }
    }

    uint4 uy[4];
    auto ISSUE_Y = [&](int s){
        const u16* yp = y1 + ((size_t)b*N_ + n0g + s*64 + r2*2)*C1_ + q16*16;
        #pragma unroll
        for (int e = 0; e < 2; ++e)
            #pragma unroll
            for (int c = 0; c < 2; ++c)
                uy[e*2+c] = *(const uint4*)(yp + (size_t)e*C1_ + c*8);
    };
    auto COMBINE = [&](char* Z){
        #pragma unroll
        for (int e = 0; e < 2; ++e)
            #pragma unroll
            for (int c = 0; c < 2; ++c){
                float f[8]; EXT8(f, uy[e*2+c]);
                u16 h[8];
                #pragma unroll
                for (int k = 0; k < 8; ++k){
                    float z = fmaf(la8[c*8+k], f[k], lc8[c*8+k]);
                    h[k] = f2bf(z > 0.f ? z : 0.f);
                }
                *(uint4*)(Z + SWZ2(r2*2+e, q16*32 + c*16)) = pack8(h);
            }
    };

    char* Zc = sm;
    char* Zn = sm + 32*1024;

    ISSUE_Y(0);
    COMBINE(Zc);
    __syncthreads();

    float s1a[4] = {0,0,0,0}, s2a[4] = {0,0,0,0};
    const int kgB = nhi*16;

    #pragma unroll 1
    for (int s = 0; s < NSUB_; ++s){
        if (s+1 < NSUB_) ISSUE_Y(s+1);
        #pragma unroll
        for (int rowg = 0; rowg < 4; ++rowg){
            int nrow = rowg*16 + nlo;
            f32x4 acc = {0.f,0.f,0.f,0.f};
            #pragma unroll
            for (int hf = 0; hf < 2; ++hf){
                bf16x8 xf[4];
                #pragma unroll
                for (int k4 = 0; k4 < 4; ++k4)
                    xf[k4] = *(const bf16x8*)(Zc + SWZ2(nrow, (hf*4+k4)*64 + kgB));
                #pragma unroll
                for (int k4 = 0; k4 < 4; ++k4)
                    acc = __builtin_amdgcn_mfma_f32_16x16x32_bf16(wfr[hf*4+k4], xf[k4], acc, 0,0,0);
            }
            int n = n0g + s*64 + nrow;
            u16 h[4];
            #pragma unroll
            for (int r = 0; r < 4; ++r){
                h[r] = f2bf(acc[r]);
                s1a[r] += acc[r]; s2a[r] += acc[r]*acc[r];
            }
            uint2 p;
            p.x = (u32)h[0] | ((u32)h[1]<<16); p.y = (u32)h[2] | ((u32)h[3]<<16);
            *(uint2*)(z2bf + ((size_t)b*N_ + n)*C2_ + wave*16 + nhi*4) = p;
        }
        if (s+1 < NSUB_) COMBINE(Zn);
        __syncthreads();
        char* tmp = Zc; Zc = Zn; Zn = tmp;
    }

    int blk = blockIdx.y * gridDim.x + blockIdx.x;
    #pragma unroll
    for (int r = 0; r < 4; ++r){
        float a = s1a[r], qv = s2a[r];
        #pragma unroll
        for (int m = 1; m <= 8; m <<= 1){ a += __shfl_xor(a, m); qv += __shfl_xor(qv, m); }
        if (nlo == 0){
            int ch = wave*16 + nhi*4 + r;
            part2[(size_t)blk*C2_ + ch] = a;
            part2[(size_t)256*C2_ + (size_t)blk*C2_ + ch] = qv;
        }
    }
}

// ---------------- finalize BN stats ----------------
__global__ void k_finalize(const float* __restrict__ part, int C, int NB, float count,
                           const float* __restrict__ gamma, const float* __restrict__ beta,
                           float* __restrict__ ac){
    int o = blockIdx.x, t = threadIdx.x;
    float s1 = 0.f, s2 = 0.f;
    for (int i = t; i < NB; i += 256){
        s1 += part[(size_t)i*C + o];
        s2 += part[(size_t)NB*C + (size_t)i*C + o];
    }
    #pragma unroll
    for (int m = 1; m < 64; m <<= 1){ s1 += __shfl_xor(s1, m); s2 += __shfl_xor(s2, m); }
    __shared__ float ls[8];
    int wave = t >> 6, lane = t & 63;
    if (lane == 0){ ls[wave] = s1; ls[4+wave] = s2; }
    __syncthreads();
    if (t == 0){
        s1 = ls[0]+ls[1]+ls[2]+ls[3];
        s2 = ls[4]+ls[5]+ls[6]+ls[7];
        float mean = s1 / count;
        float var  = s2 / count - mean*mean;
        float inv  = rsqrtf(var + 1e-5f);
        float a = gamma[o] * inv;
        ac[o] = a;
        ac[C + o] = beta[o] - mean*a;
    }
}

// ---------------- apply BN2+ReLU with transpose: z2bf [b][n][ch] -> out [b][ch][n] f32 ----------------
__global__ __launch_bounds__(256) void k_apply(const u16* __restrict__ z2bf,
                                               const float* __restrict__ a2c2,
                                               float* __restrict__ out){
    __shared__ float T[128][65];
    __shared__ float la[C2_], lc[C2_];
    int b = blockIdx.y, n0 = blockIdx.x * 64;
    int t = threadIdx.x;
    if (t < C2_){ la[t] = a2c2[t]; lc[t] = a2c2[C2_ + t]; }
    __syncthreads();
    int ck = t & 15, ng = t >> 4;
    #pragma unroll
    for (int g = 0; g < 4; ++g){
        int n = g*16 + ng;
        uint4 v = *(const uint4*)(z2bf + ((size_t)b*N_ + n0 + n)*C2_ + ck*8);
        float f[8]; EXT8(f, v);
        #pragma unroll
        for (int e = 0; e < 8; ++e){
            int ch = ck*8 + e;
            T[ch][n] = fmaxf(fmaf(la[ch], f[e], lc[ch]), 0.f);
        }
    }
    __syncthreads();
    #pragma unroll
    for (int g = 0; g < 8; ++g){
        int id = g*256 + t;
        int ch = id >> 4, f4 = id & 15;
        float4 o;
        o.x = T[ch][f4*4+0]; o.y = T[ch][f4*4+1];
        o.z = T[ch][f4*4+2]; o.w = T[ch][f4*4+3];
        *(float4*)(out + ((size_t)b*C2_ + ch)*N_ + n0 + f4*4) = o;
    }
}

extern "C" void kernel_launch(void* const* d_in, const int* in_sizes, int n_in,
                              void* d_out, int out_size, void* d_ws, size_t ws_size,
                              hipStream_t stream){
    const float* xyz1    = (const float*)d_in[0];
    const float* xyz2    = (const float*)d_in[1];
    const float* points1 = (const float*)d_in[2];
    const float* points2 = (const float*)d_in[3];
    const float* w1      = (const float*)d_in[4];
    const float* gamma1  = (const float*)d_in[6];
    const float* beta1   = (const float*)d_in[7];
    const float* w2      = (const float*)d_in[8];
    const float* gamma2  = (const float*)d_in[10];
    const float* beta2   = (const float*)d_in[11];
    float* outp = (float*)d_out;

    char* ws = (char*)d_ws;
    size_t off = 0;
    auto take = [&](size_t sz) -> void* {
        void* p = ws + off;
        off = (off + sz + 255) & ~(size_t)255;
        return p;
    };
    int4*   nn_idx4 = (int4*)  take((size_t)B_*N_*16);
    float4* nn_w4   = (float4*)take((size_t)B_*N_*16);
    u16*    w1bf    = (u16*)   take((size_t)C1_*CIN_*2);
    u16*    w2bf    = (u16*)   take((size_t)C2_*C1_*2);
    u16*    p2t     = (u16*)   take((size_t)B_*S_*D2_*2);
    u16*    y1      = (u16*)   take((size_t)B_*N_*C1_*2);
    u16*    z2bf    = (u16*)   take((size_t)B_*N_*C2_*2);
    float*  part1   = (float*) take((size_t)2*256*C1_*4);
    float*  part2   = (float*) take((size_t)2*256*C2_*4);
    float*  a1c1    = (float*) take((size_t)2*C1_*4);
    float*  a2c2    = (float*) take((size_t)2*C2_*4);

    hipLaunchKernelGGL(k_prep_w, dim3(384), dim3(256), 0, stream, w1, w2, w1bf, w2bf);
    hipLaunchKernelGGL(k_p2t, dim3(S_/32, D2_/32, B_), dim3(256), 0, stream, points2, p2t);
    hipLaunchKernelGGL(k_nn, dim3(N_/64, B_), dim3(256), 0, stream, xyz1, xyz2, nn_idx4, nn_w4);
    hipLaunchKernelGGL(k_conv1, dim3(256), dim3(512), 0, stream,
                       w1bf, points1, p2t, nn_idx4, nn_w4, y1, part1);
    hipLaunchKernelGGL(k_finalize, dim3(C1_), dim3(256), 0, stream,
                       part1, C1_, 256, (float)(B_*N_), gamma1, beta1, a1c1);
    hipLaunchKernelGGL(k_conv2, dim3(N_/256, B_), dim3(512), 0, stream,
                       w2bf, y1, a1c1, z2bf, part2);
    hipLaunchKernelGGL(k_finalize, dim3(C2_), dim3(256), 0, stream,
                       part2, C2_, 256, (float)(B_*N_), gamma2, beta2, a2c2);
    hipLaunchKernelGGL(k_apply, dim3(N_/64, B_), dim3(256), 0, stream, z2bf, a2c2, outp);
    (void)in_sizes; (void)n_in; (void)out_size; (void)ws_size; (void)d_in;
}

// Round 8
// 176.149 us; speedup vs baseline: 1.6005x; 1.2068x over previous
//
#include <hip/hip_runtime.h>
#include <stdint.h>

#define B_   8
#define N_   8192
#define S_   2048
#define D1_  128
#define D2_  256
#define CIN_ 384
#define C1_  256
#define C2_  128
#define NSUB_ 4

typedef uint16_t u16;
typedef uint32_t u32;
typedef __attribute__((ext_vector_type(8))) short bf16x8;
typedef __attribute__((ext_vector_type(4))) float f32x4;

static __device__ __forceinline__ u16 f2bf(float f){
    union { float f; u32 u; } v; v.f = f;
    u32 r = v.u + 0x7FFF + ((v.u >> 16) & 1);
    return (u16)(r >> 16);
}
static __device__ __forceinline__ float bf2f(u16 h){
    union { u32 u; float f; } v; v.u = ((u32)h) << 16;
    return v.f;
}
static __device__ __forceinline__ uint4 pack8(const u16 h[8]){
    uint4 u;
    u.x = (u32)h[0] | ((u32)h[1] << 16);
    u.y = (u32)h[2] | ((u32)h[3] << 16);
    u.z = (u32)h[4] | ((u32)h[5] << 16);
    u.w = (u32)h[6] | ((u32)h[7] << 16);
    return u;
}
#define EXT8(dst, u) { dst[0]=bf2f((u16)(u).x); dst[1]=bf2f((u16)((u).x>>16)); \
                       dst[2]=bf2f((u16)(u).y); dst[3]=bf2f((u16)((u).y>>16)); \
                       dst[4]=bf2f((u16)(u).z); dst[5]=bf2f((u16)((u).z>>16)); \
                       dst[6]=bf2f((u16)(u).w); dst[7]=bf2f((u16)((u).w>>16)); }

static __device__ __forceinline__ float med3f(float a, float b, float c){
    float d;
    asm("v_med3_f32 %0, %1, %2, %3" : "=v"(d) : "v"(a), "v"(b), "v"(c));
    return d;
}

// ---------------- prep: weights -> bf16 ----------------
__global__ void k_prep_w(const float* __restrict__ w1, const float* __restrict__ w2,
                         u16* __restrict__ w1bf, u16* __restrict__ w2bf){
    int i = blockIdx.x * 256 + threadIdx.x;
    if (i < C1_*CIN_) w1bf[i] = f2bf(w1[i]);
    if (i < C2_*C1_)  w2bf[i] = f2bf(w2[i]);
}

// ---------------- prep: points2 [b][d][s] -> p2t bf16 [b][s][d] ----------------
__global__ __launch_bounds__(256) void k_p2t(const float* __restrict__ p2, u16* __restrict__ p2t){
    __shared__ float t[32][33];
    int b = blockIdx.z, s0 = blockIdx.x * 32, d0 = blockIdx.y * 32;
    int tt = threadIdx.x;
    int r = tt >> 3, c4 = (tt & 7) * 4;
    const float* src = p2 + (((size_t)b*D2_ + d0 + r) * S_ + s0 + c4);
    float4 v = *(const float4*)src;
    t[r][c4+0]=v.x; t[r][c4+1]=v.y; t[r][c4+2]=v.z; t[r][c4+3]=v.w;
    __syncthreads();
    ushort4 o;
    o.x = f2bf(t[c4+0][r]); o.y = f2bf(t[c4+1][r]);
    o.z = f2bf(t[c4+2][r]); o.w = f2bf(t[c4+3][r]);
    u16* dst = p2t + (((size_t)b*S_ + s0 + r) * D2_ + d0 + c4);
    *(ushort4*)dst = o;
}

// ---------------- 3-NN search: score-max formulation, med3 sorted-insert ----------------
#define INSMAX(sc, s) do{ \
    bool c2 = (sc) > M2, c1 = (sc) > M1, c0 = (sc) > M0; \
    int I2n = c2 ? (c1 ? I1 : (s)) : I2; \
    int I1n = c1 ? (c0 ? I0 : (s)) : I1; \
    int I0n = c0 ? (s) : I0; \
    float M2n = med3f(M1, M2, (sc)); \
    float M1n = med3f(M0, M1, (sc)); \
    M0 = fmaxf(M0, (sc)); \
    M1 = M1n; M2 = M2n; I0 = I0n; I1 = I1n; I2 = I2n; \
}while(0)
#define INSMAXB(sc, s) do{ \
    bool c2 = (sc) > N2, c1 = (sc) > N1, c0 = (sc) > N0; \
    int J2n = c2 ? (c1 ? J1 : (s)) : J2; \
    int J1n = c1 ? (c0 ? J0 : (s)) : J1; \
    int J0n = c0 ? (s) : J0; \
    float N2n = med3f(N1, N2, (sc)); \
    float N1n = med3f(N0, N1, (sc)); \
    N0 = fmaxf(N0, (sc)); \
    N1 = N1n; N2 = N2n; J0 = J0n; J1 = J1n; J2 = J2n; \
}while(0)

__global__ __launch_bounds__(256) void k_nn(const float* __restrict__ xyz1,
                                            const float* __restrict__ xyz2,
                                            int4* __restrict__ nn_idx4, float4* __restrict__ nn_w4){
    __shared__ float4 pt[4*513];             // quarter q at pt + q*513 (16B pad between)
    int b = blockIdx.y;
    int t = threadIdx.x;
    const float* xb = xyz2 + (size_t)b*3*S_;
    for (int i = t; i < S_; i += 256){
        float x = xb[i], y = xb[S_ + i], z = xb[2*S_ + i];
        float hw = 0.5f*(x*x + y*y + z*z);
        pt[(i >> 9)*513 + (i & 511)] = make_float4(x, y, z, hw);
    }
    __syncthreads();
    int nl = t >> 2, q = t & 3;              // 64 queries/block, 4 threads each
    int n = blockIdx.x * 64 + nl;
    const float* x1b = xyz1 + (size_t)b*3*N_;
    float px = x1b[n], py = x1b[N_ + n], pz = x1b[2*N_ + n];
    float n1 = px*px + py*py + pz*pz;
    float M0 = -3.4e38f, M1 = -3.4e38f, M2 = -3.4e38f;
    float N0 = -3.4e38f, N1 = -3.4e38f, N2 = -3.4e38f;
    int I0 = 0, I1 = 0, I2 = 0, J0 = 0, J1 = 0, J2 = 0;
    const float4* ptq = pt + q*513;
    #pragma unroll 4
    for (int j = 0; j < 512; j += 2){
        float4 qa = ptq[j];
        float4 qb = ptq[j+1];
        float sa = fmaf(px, qa.x, fmaf(py, qa.y, fmaf(pz, qa.z, -qa.w)));
        float sb = fmaf(px, qb.x, fmaf(py, qb.y, fmaf(pz, qb.z, -qb.w)));
        INSMAX(sa, j);
        INSMAXB(sb, j+1);
    }
    INSMAX(N0, J0); INSMAX(N1, J1); INSMAX(N2, J2);
    int sQ = q * 512;
    I0 += sQ; I1 += sQ; I2 += sQ;
    #pragma unroll
    for (int m = 1; m <= 2; m <<= 1){
        float e0=__shfl_xor(M0,m), e1=__shfl_xor(M1,m), e2=__shfl_xor(M2,m);
        int   j0=__shfl_xor(I0,m), j1=__shfl_xor(I1,m), j2=__shfl_xor(I2,m);
        INSMAX(e0, j0); INSMAX(e1, j1); INSMAX(e2, j2);
    }
    if (q == 0){
        float d0 = fmaf(-2.f, M0, n1);
        float d1 = fmaf(-2.f, M1, n1);
        float d2 = fmaf(-2.f, M2, n1);
        float r0 = 1.f/(d0+1e-8f), r1 = 1.f/(d1+1e-8f), r2 = 1.f/(d2+1e-8f);
        float inv = 1.f/(r0+r1+r2);
        size_t base = (size_t)b*N_ + n;
        nn_idx4[base] = make_int4(I0, I1, I2, 0);
        nn_w4[base]   = make_float4(r0*inv, r1*inv, r2*inv, 0.f);
    }
}

// LDS swizzles: Xt row=768B, Zt row=512B
#define SWZ(nrow, kbyte)  ((((nrow)*768 + (kbyte))) ^ (((nrow)&7)<<4))
#define SWZ2(nrow, kbyte) ((((nrow)*512 + (kbyte))) ^ (((nrow)&7)<<4))

// ---------------- conv1 v3: designed for <=128 VGPR (no spills possible) ----------------
// Round-7 post-mortem: allocator pins 128 arch VGPRs regardless of launch_bounds /
// waves_per_eu; old structure demanded ~220 -> ~37MB of scratch spill writes in the
// inner loop = the 89us. v3: wave owns 16 ch (wfr[12]=48 VGPR); 2 sequential channel
// passes reload wfr from L2 (192KB W1 is L2-resident); 128-point tile built once
// (2x48KB LDS), consumed by both passes. unroll-1 on every buffer-replicating loop.
__global__ __launch_bounds__(512, 2)
void k_conv1(const u16* __restrict__ w1bf,
    const float* __restrict__ points1, const u16* __restrict__ p2t,
    const int4* __restrict__ nn_idx4, const float4* __restrict__ nn_w4,
    u16* __restrict__ y1, float* __restrict__ part1){
    __shared__ char sm[96*1024];
    int t = threadIdx.x;
    int wave = t >> 6, lane = t & 63;
    int b = blockIdx.y, n0g = blockIdx.x * 128;
    const int nlo = lane & 15, nhi = lane >> 4;
    const int g8 = t & 15, pr = t >> 4;   // phase A roles: 8-ch group, row-pair
    const int rb = t >> 3, q8 = t & 7;    // phase B roles: row, 32-ch group

    // ---- build both 64-row subtiles (sequential; transient registers only)
    #pragma unroll 1
    for (int sub = 0; sub < 2; ++sub){
        char* X = sm + sub*48*1024;
        float2 va2[8];
        const float* pA = points1 + ((size_t)b*D1_ + g8*8)*N_ + n0g + sub*64 + pr*2;
        #pragma unroll
        for (int j = 0; j < 8; ++j) va2[j] = *(const float2*)(pA + (size_t)j*N_);
        size_t nb = (size_t)b*N_ + n0g + sub*64 + rb;
        int4 nid = nn_idx4[nb];
        float4 nw = nn_w4[nb];
        const u16* r0 = p2t + ((size_t)b*S_ + nid.x)*D2_ + q8*32;
        const u16* r1 = p2t + ((size_t)b*S_ + nid.y)*D2_ + q8*32;
        const u16* r2 = p2t + ((size_t)b*S_ + nid.z)*D2_ + q8*32;
        uint4 uB[12];
        #pragma unroll
        for (int c = 0; c < 4; ++c){
            uB[c]   = *(const uint4*)(r0 + c*8);
            uB[4+c] = *(const uint4*)(r1 + c*8);
            uB[8+c] = *(const uint4*)(r2 + c*8);
        }
        #pragma unroll
        for (int e = 0; e < 2; ++e){
            u16 h[8];
            #pragma unroll
            for (int j = 0; j < 8; ++j) h[j] = f2bf(e ? va2[j].y : va2[j].x);
            *(uint4*)(X + SWZ(pr*2+e, g8*16)) = pack8(h);
        }
        #pragma unroll
        for (int c = 0; c < 4; ++c){
            float f0[8], f1[8], f2v[8];
            EXT8(f0, uB[c]); EXT8(f1, uB[4+c]); EXT8(f2v, uB[8+c]);
            u16 h[8];
            #pragma unroll
            for (int e = 0; e < 8; ++e)
                h[e] = f2bf(fmaf(nw.x, f0[e], fmaf(nw.y, f1[e], nw.z*f2v[e])));
            *(uint4*)(X + SWZ(rb, (128 + q8*32 + c*8)*2)) = pack8(h);
        }
    }
    __syncthreads();

    // ---- two channel passes; wfr reloaded per pass (L2-resident W1)
    int blk = blockIdx.y * gridDim.x + blockIdx.x;
    #pragma unroll 1
    for (int pass = 0; pass < 2; ++pass){
        bf16x8 wfr[12];
        {
            const u16* wb = w1bf + ((size_t)(pass*128 + wave*16 + nlo))*CIN_ + nhi*8;
            #pragma unroll
            for (int ks = 0; ks < 12; ++ks) wfr[ks] = *(const bf16x8*)(wb + ks*32);
        }
        float s1a[4] = {0,0,0,0}, s2a[4] = {0,0,0,0};
        #pragma unroll 1
        for (int sub = 0; sub < 2; ++sub){
            char* X = sm + sub*48*1024;
            #pragma unroll 1
            for (int rowg = 0; rowg < 4; ++rowg){
                int nrow = rowg*16 + nlo;
                f32x4 acc = {0.f,0.f,0.f,0.f};
                #pragma unroll
                for (int hf = 0; hf < 2; ++hf){
                    bf16x8 xf[6];
                    #pragma unroll
                    for (int k6 = 0; k6 < 6; ++k6)
                        xf[k6] = *(const bf16x8*)(X + SWZ(nrow, (hf*6+k6)*64 + nhi*16));
                    #pragma unroll
                    for (int k6 = 0; k6 < 6; ++k6)
                        acc = __builtin_amdgcn_mfma_f32_16x16x32_bf16(wfr[hf*6+k6], xf[k6], acc, 0,0,0);
                }
                int n = n0g + sub*64 + nrow;
                u16 h[4];
                #pragma unroll
                for (int r = 0; r < 4; ++r){
                    h[r] = f2bf(acc[r]);
                    s1a[r] += acc[r]; s2a[r] += acc[r]*acc[r];
                }
                uint2 p;
                p.x = (u32)h[0] | ((u32)h[1]<<16); p.y = (u32)h[2] | ((u32)h[3]<<16);
                *(uint2*)(y1 + ((size_t)b*N_ + n)*C1_ + pass*128 + wave*16 + nhi*4) = p;
            }
        }
        // BN1 partials for this pass's channels
        #pragma unroll
        for (int r = 0; r < 4; ++r){
            float a = s1a[r], qv = s2a[r];
            #pragma unroll
            for (int m = 1; m <= 8; m <<= 1){ a += __shfl_xor(a, m); qv += __shfl_xor(qv, m); }
            if (nlo == 0){
                int ch = pass*128 + wave*16 + nhi*4 + r;
                part1[(size_t)blk*C1_ + ch] = a;
                part1[(size_t)512*C1_ + (size_t)blk*C1_ + ch] = qv;
            }
        }
    }
}

// ---------------- conv2: W-stationary, z = relu(bn1(y1)) on the fly ----------------
__global__ __launch_bounds__(512, 4) void k_conv2(const u16* __restrict__ w2bf,
    const u16* __restrict__ y1, const float* __restrict__ a1c1,
    u16* __restrict__ z2bf, float* __restrict__ part2){
    __shared__ char sm[64*1024];
    int t = threadIdx.x;
    int wave = t >> 6, lane = t & 63;
    int b = blockIdx.y, n0g = blockIdx.x * 256;
    const int nlo = lane & 15, nhi = lane >> 4;

    bf16x8 wfr[8];
    {
        const u16* wb = w2bf + ((size_t)(wave*16 + nlo))*C1_ + nhi*8;
        #pragma unroll
        for (int ks = 0; ks < 8; ++ks) wfr[ks] = *(const bf16x8*)(wb + ks*32);
    }

    const int r2 = t >> 4, q16 = t & 15;   // build roles: row-pair, 16-ch group
    float la8[16], lc8[16];
    {
        const float* ap = a1c1 + q16*16;
        #pragma unroll
        for (int c = 0; c < 4; ++c){
            *(float4*)(la8 + c*4) = *(const float4*)(ap + c*4);
            *(float4*)(lc8 + c*4) = *(const float4*)(ap + 256 + c*4);
        }
    }

    uint4 uy[4];
    auto ISSUE_Y = [&](int s){
        const u16* yp = y1 + ((size_t)b*N_ + n0g + s*64 + r2*2)*C1_ + q16*16;
        #pragma unroll
        for (int e = 0; e < 2; ++e)
            #pragma unroll
            for (int c = 0; c < 2; ++c)
                uy[e*2+c] = *(const uint4*)(yp + (size_t)e*C1_ + c*8);
    };
    auto COMBINE = [&](char* Z){
        #pragma unroll
        for (int e = 0; e < 2; ++e)
            #pragma unroll
            for (int c = 0; c < 2; ++c){
                float f[8]; EXT8(f, uy[e*2+c]);
                u16 h[8];
                #pragma unroll
                for (int k = 0; k < 8; ++k){
                    float z = fmaf(la8[c*8+k], f[k], lc8[c*8+k]);
                    h[k] = f2bf(z > 0.f ? z : 0.f);
                }
                *(uint4*)(Z + SWZ2(r2*2+e, q16*32 + c*16)) = pack8(h);
            }
    };

    char* Zc = sm;
    char* Zn = sm + 32*1024;

    ISSUE_Y(0);
    COMBINE(Zc);
    __syncthreads();

    float s1a[4] = {0,0,0,0}, s2a[4] = {0,0,0,0};
    const int kgB = nhi*16;

    #pragma unroll 1
    for (int s = 0; s < NSUB_; ++s){
        if (s+1 < NSUB_) ISSUE_Y(s+1);
        #pragma unroll
        for (int rowg = 0; rowg < 4; ++rowg){
            int nrow = rowg*16 + nlo;
            f32x4 acc = {0.f,0.f,0.f,0.f};
            #pragma unroll
            for (int hf = 0; hf < 2; ++hf){
                bf16x8 xf[4];
                #pragma unroll
                for (int k4 = 0; k4 < 4; ++k4)
                    xf[k4] = *(const bf16x8*)(Zc + SWZ2(nrow, (hf*4+k4)*64 + kgB));
                #pragma unroll
                for (int k4 = 0; k4 < 4; ++k4)
                    acc = __builtin_amdgcn_mfma_f32_16x16x32_bf16(wfr[hf*4+k4], xf[k4], acc, 0,0,0);
            }
            int n = n0g + s*64 + nrow;
            u16 h[4];
            #pragma unroll
            for (int r = 0; r < 4; ++r){
                h[r] = f2bf(acc[r]);
                s1a[r] += acc[r]; s2a[r] += acc[r]*acc[r];
            }
            uint2 p;
            p.x = (u32)h[0] | ((u32)h[1]<<16); p.y = (u32)h[2] | ((u32)h[3]<<16);
            *(uint2*)(z2bf + ((size_t)b*N_ + n)*C2_ + wave*16 + nhi*4) = p;
        }
        if (s+1 < NSUB_) COMBINE(Zn);
        __syncthreads();
        char* tmp = Zc; Zc = Zn; Zn = tmp;
    }

    int blk = blockIdx.y * gridDim.x + blockIdx.x;
    #pragma unroll
    for (int r = 0; r < 4; ++r){
        float a = s1a[r], qv = s2a[r];
        #pragma unroll
        for (int m = 1; m <= 8; m <<= 1){ a += __shfl_xor(a, m); qv += __shfl_xor(qv, m); }
        if (nlo == 0){
            int ch = wave*16 + nhi*4 + r;
            part2[(size_t)blk*C2_ + ch] = a;
            part2[(size_t)256*C2_ + (size_t)blk*C2_ + ch] = qv;
        }
    }
}

// ---------------- finalize BN stats ----------------
__global__ void k_finalize(const float* __restrict__ part, int C, int NB, float count,
                           const float* __restrict__ gamma, const float* __restrict__ beta,
                           float* __restrict__ ac){
    int o = blockIdx.x, t = threadIdx.x;
    float s1 = 0.f, s2 = 0.f;
    for (int i = t; i < NB; i += 256){
        s1 += part[(size_t)i*C + o];
        s2 += part[(size_t)NB*C + (size_t)i*C + o];
    }
    #pragma unroll
    for (int m = 1; m < 64; m <<= 1){ s1 += __shfl_xor(s1, m); s2 += __shfl_xor(s2, m); }
    __shared__ float ls[8];
    int wave = t >> 6, lane = t & 63;
    if (lane == 0){ ls[wave] = s1; ls[4+wave] = s2; }
    __syncthreads();
    if (t == 0){
        s1 = ls[0]+ls[1]+ls[2]+ls[3];
        s2 = ls[4]+ls[5]+ls[6]+ls[7];
        float mean = s1 / count;
        float var  = s2 / count - mean*mean;
        float inv  = rsqrtf(var + 1e-5f);
        float a = gamma[o] * inv;
        ac[o] = a;
        ac[C + o] = beta[o] - mean*a;
    }
}

// ---------------- apply BN2+ReLU with transpose: z2bf [b][n][ch] -> out [b][ch][n] f32 ----------------
__global__ __launch_bounds__(256) void k_apply(const u16* __restrict__ z2bf,
                                               const float* __restrict__ a2c2,
                                               float* __restrict__ out){
    __shared__ float T[128][65];
    __shared__ float la[C2_], lc[C2_];
    int b = blockIdx.y, n0 = blockIdx.x * 64;
    int t = threadIdx.x;
    if (t < C2_){ la[t] = a2c2[t]; lc[t] = a2c2[C2_ + t]; }
    __syncthreads();
    int ck = t & 15, ng = t >> 4;
    #pragma unroll
    for (int g = 0; g < 4; ++g){
        int n = g*16 + ng;
        uint4 v = *(const uint4*)(z2bf + ((size_t)b*N_ + n0 + n)*C2_ + ck*8);
        float f[8]; EXT8(f, v);
        #pragma unroll
        for (int e = 0; e < 8; ++e){
            int ch = ck*8 + e;
            T[ch][n] = fmaxf(fmaf(la[ch], f[e], lc[ch]), 0.f);
        }
    }
    __syncthreads();
    #pragma unroll
    for (int g = 0; g < 8; ++g){
        int id = g*256 + t;
        int ch = id >> 4, f4 = id & 15;
        float4 o;
        o.x = T[ch][f4*4+0]; o.y = T[ch][f4*4+1];
        o.z = T[ch][f4*4+2]; o.w = T[ch][f4*4+3];
        *(float4*)(out + ((size_t)b*C2_ + ch)*N_ + n0 + f4*4) = o;
    }
}

extern "C" void kernel_launch(void* const* d_in, const int* in_sizes, int n_in,
                              void* d_out, int out_size, void* d_ws, size_t ws_size,
                              hipStream_t stream){
    const float* xyz1    = (const float*)d_in[0];
    const float* xyz2    = (const float*)d_in[1];
    const float* points1 = (const float*)d_in[2];
    const float* points2 = (const float*)d_in[3];
    const float* w1      = (const float*)d_in[4];
    const float* gamma1  = (const float*)d_in[6];
    const float* beta1   = (const float*)d_in[7];
    const float* w2      = (const float*)d_in[8];
    const float* gamma2  = (const float*)d_in[10];
    const float* beta2   = (const float*)d_in[11];
    float* outp = (float*)d_out;

    char* ws = (char*)d_ws;
    size_t off = 0;
    auto take = [&](size_t sz) -> void* {
        void* p = ws + off;
        off = (off + sz + 255) & ~(size_t)255;
        return p;
    };
    int4*   nn_idx4 = (int4*)  take((size_t)B_*N_*16);
    float4* nn_w4   = (float4*)take((size_t)B_*N_*16);
    u16*    w1bf    = (u16*)   take((size_t)C1_*CIN_*2);
    u16*    w2bf    = (u16*)   take((size_t)C2_*C1_*2);
    u16*    p2t     = (u16*)   take((size_t)B_*S_*D2_*2);
    u16*    y1      = (u16*)   take((size_t)B_*N_*C1_*2);
    u16*    z2bf    = (u16*)   take((size_t)B_*N_*C2_*2);
    float*  part1   = (float*) take((size_t)2*512*C1_*4);
    float*  part2   = (float*) take((size_t)2*256*C2_*4);
    float*  a1c1    = (float*) take((size_t)2*C1_*4);
    float*  a2c2    = (float*) take((size_t)2*C2_*4);

    hipLaunchKernelGGL(k_prep_w, dim3(384), dim3(256), 0, stream, w1, w2, w1bf, w2bf);
    hipLaunchKernelGGL(k_p2t, dim3(S_/32, D2_/32, B_), dim3(256), 0, stream, points2, p2t);
    hipLaunchKernelGGL(k_nn, dim3(N_/64, B_), dim3(256), 0, stream, xyz1, xyz2, nn_idx4, nn_w4);
    hipLaunchKernelGGL(k_conv1, dim3(N_/128, B_), dim3(512), 0, stream,
                       w1bf, points1, p2t, nn_idx4, nn_w4, y1, part1);
    hipLaunchKernelGGL(k_finalize, dim3(C1_), dim3(256), 0, stream,
                       part1, C1_, 512, (float)(B_*N_), gamma1, beta1, a1c1);
    hipLaunchKernelGGL(k_conv2, dim3(N_/256, B_), dim3(512), 0, stream,
                       w2bf, y1, a1c1, z2bf, part2);
    hipLaunchKernelGGL(k_finalize, dim3(C2_), dim3(256), 0, stream,
                       part2, C2_, 256, (float)(B_*N_), gamma2, beta2, a2c2);
    hipLaunchKernelGGL(k_apply, dim3(N_/64, B_), dim3(256), 0, stream, z2bf, a2c2, outp);
    (void)in_sizes; (void)n_in; (void)out_size; (void)ws_size; (void)d_in;
}